// Round 17
// baseline (103.550 us; speedup 1.0000x reference)
//
#include <hip/hip_runtime.h>
#include <hip/hip_bf16.h>

// FirUpsample R16 = R15 schedule + two shared-port fixes (model: L1 line-
// serialization ~74us/CU from the w-gather + LDS ~53us/CU incl 19us of A-read
// bank conflicts; ports overlap -> invariant ~100us):
//   (a) A-stage: lane-consecutive float4 loads over the flat 2304-f4 chunk
//       slice (~17 lines/instr vs ~72), ALL decode (oc, ic, kq, swizzled
//       write offsets) precomputed once (chunk-invariant) -> no div/mod
//       in-loop; 18 precomputed b16 scatter writes.
//   (b) As 16B-slot XOR swizzle s^=(s>>3)&7 (write AND read side): fragment
//       reads hit all 8 bank quads (was 2x conflicted, =1.16e7 cycles).
// Math (verified R5-R15, absmax 0.015625): h = dilated conv3x3 as 4 parity-
// plane GEMMs (10.3 G MAC); separable 4-tap FIR epilogue from LDS.

typedef short bf16x8 __attribute__((ext_vector_type(8)));
typedef short short4v __attribute__((ext_vector_type(4)));
typedef float f32x16 __attribute__((ext_vector_type(16)));
typedef float f32x4v __attribute__((ext_vector_type(4)));

static __device__ __forceinline__ short f2bf(float f) {
  __hip_bfloat16 h = __float2bfloat16(f);
  union { __hip_bfloat16 h; short s; } u; u.h = h;
  return u.s;
}
static __device__ __forceinline__ float bf2f(short s) {
  union { unsigned u; float f; } v; v.u = ((unsigned)(unsigned short)s) << 16;
  return v.f;
}
static __device__ __forceinline__ int swz(int off) {  // within one 2048B kq-plane
  int s = off >> 4;
  s ^= (s >> 3) & 7;
  return (s << 4) | (off & 15);
}

#define AS_SZ 18432           // one As buffer: [9 kq][64 oc][16 ic] bf16 (swizzled slots)
#define XS_BASE 36864         // 2*AS_SZ
#define XS_SZ 8640            // one xs buffer: [180 cells][48 B]
#define XS_STRIDE 48

__global__ __launch_bounds__(512, 2)
void fir_up_v16(const float* __restrict__ x, const float* __restrict__ w,
                float* __restrict__ out) {
  __shared__ __align__(16) char smem[54144];

  const int bid = blockIdx.x;
  const int wg = (bid & 7) * 64 + (bid >> 3);
  const int octile = wg >> 7;        // 0..3 (64 oc each)
  const int n = (wg >> 5) & 3;
  const int sp = wg & 31;
  const int atile = sp >> 2;
  const int btile = sp & 3;
  const int A0 = atile * 8, B0 = btile * 16;

  const int tid = threadIdx.x;
  const int wid = tid >> 6;
  const int lane = tid & 63;
  const int l31 = lane & 31, q = lane >> 5;

  // ---- plane geometry + per-wave partition (verbatim R13-R15, verified) ----
  const int COLSt[4]  = {17, 18, 17, 18};
  const int CELLSt[4] = {153, 162, 170, 180};
  const int NKt[4]    = {4, 2, 2, 1};
  const int KQt[4][4] = {{0,2,6,8},{1,7,7,7},{3,5,5,5},{4,4,4,4}};
  const int DYt[4][4] = {{0,0,1,1},{0,1,1,1},{0,0,0,0},{0,0,0,0}};
  const int DXt[4][4] = {{0,1,0,1},{0,0,0,0},{0,1,1,1},{0,0,0,0}};
  const unsigned long long PLbits =
      (0x34ULL) | (0x34ULL << 6) | (0x34ULL << 12) | (0x38ULL << 18) |
      (0x38ULL << 24) | (0x38ULL << 30) | (0x15ULL << 36) | (0x2AULL << 42);
  const unsigned FG0 = 0u | 1u<<3 | 2u<<6 | 3u<<9 | 4u<<12 | 5u<<15 | 3u<<18 | 3u<<21;
  const unsigned FG1 = 0u | 1u<<3 | 2u<<6 | 0u<<9 | 1u<<12 | 2u<<15 | 4u<<18 | 4u<<21;
  const unsigned FG2 = 0u | 1u<<3 | 2u<<6 | 3u<<9 | 4u<<12 | 5u<<15 | 5u<<18 | 5u<<21;

  int nkS[3], validS[3], hbaseS[3];
  int kqS[3][4], cellxS[3][4];
#pragma unroll
  for (int slot = 0; slot < 3; ++slot) {
    const int p = (int)((PLbits >> ((wid * 3 + slot) * 2)) & 3ULL);
    const unsigned fgw = slot == 0 ? FG0 : (slot == 1 ? FG1 : FG2);
    const int fg = (int)((fgw >> (3 * wid)) & 7u);
    const int cellraw = fg * 32 + l31;
    const int valid = cellraw < CELLSt[p];
    const int cell = valid ? cellraw : 0;
    const int cols = COLSt[p];
    const int r = cell / cols;
    const int c = cell - r * cols;
    nkS[slot] = NKt[p];
    validS[slot] = valid;
    hbaseS[slot] = p * 6400 + r * 20 + c;
#pragma unroll
    for (int s = 0; s < 4; ++s) {
      kqS[slot][s] = KQt[p][s];
      cellxS[slot][s] = (r + DYt[p][s]) * 18 + (c + DXt[p][s]);
    }
  }

  // swizzled A-fragment base: slot s = 2*l31+q -> s' = s ^ ((s>>3)&7)
  int swzb;
  {
    int s = 2 * l31 + q;
    s ^= (s >> 3) & 7;
    swzb = s << 4;
  }

  f32x16 acc[3][2];
#pragma unroll
  for (int slot = 0; slot < 3; ++slot)
#pragma unroll
    for (int mf = 0; mf < 2; ++mf)
#pragma unroll
      for (int e = 0; e < 16; ++e) acc[slot][mf][e] = 0.f;

  // ---- A-stage precompute (chunk-invariant): 5 units of (f4 load + 4 writes) ----
  const char* wbase_b = (const char*)(w + (size_t)(octile * 64) * 2304);
  int preoff[5];     // byte offset of this unit's f4 within (oc-block, f36)
  int woff[5][4];    // LDS byte offsets (kq plane + swizzled slot)
  bool actA[5];
#pragma unroll
  for (int k = 0; k < 5; ++k) {
    const int f = tid + k * 512;
    actA[k] = f < 2304;
    const int fc = actA[k] ? f : 0;
    const int oc = fc / 36;
    const int f36 = fc - oc * 36;
    preoff[k] = oc * 9216 + f36 * 16;
#pragma unroll
    for (int e = 0; e < 4; ++e) {
      const int flat = f36 * 4 + e;
      const int ic = flat / 9;
      const int kq = flat - ic * 9;
      woff[k][e] = kq * 2048 + swz(oc * 32 + ic * 2);
    }
  }

  // ---- x-stage decode (verbatim R15; coalesced f4 rows, interior fast path) ----
  int uic_[2], urow_[2], uf4g_[2], ugh_[2], ugw0_[2], uwb0_[2];
  bool uact_[2], urowok_[2], ual_[2], uint_[2];
#pragma unroll
  for (int t = 0; t < 2; ++t) {
    const int u = tid + t * 512;
    uact_[t] = u < 960;
    const int uu = uact_[t] ? u : 0;
    uic_[t] = uu / 60;
    const int rem = uu - uic_[t] * 60;
    urow_[t] = rem / 6;
    uf4g_[t] = rem - urow_[t] * 6;
    ugh_[t] = A0 - 1 + urow_[t];
    urowok_[t] = (ugh_[t] >= 0) & (ugh_[t] < 64);
    ugw0_[t] = B0 - 4 + 4 * uf4g_[t];
    ual_[t] = (ugw0_[t] >= 0) & (ugw0_[t] <= 60);
    uint_[t] = (uf4g_[t] >= 1) & (uf4g_[t] <= 4);
    uwb0_[t] = (urow_[t] * 18 + (4 * uf4g_[t] - 3)) * XS_STRIDE + uic_[t] * 2;
  }

  // ---- prologue: stage chunk 0 into buffers 0 ----
  {
    char* xsw = smem + XS_BASE;
#pragma unroll
    for (int t = 0; t < 2; ++t) {
      if (uact_[t]) {
        float v[4] = {0.f, 0.f, 0.f, 0.f};
        if (urowok_[t]) {
          const float* base = x + (((size_t)(n * 256 + uic_[t])) * 64 + ugh_[t]) * 64;
          if (ual_[t]) {
            const f32x4v fv = *(const f32x4v*)(base + ugw0_[t]);
#pragma unroll
            for (int e = 0; e < 4; ++e) v[e] = fv[e];
          } else {
#pragma unroll
            for (int e = 0; e < 4; ++e) {
              const int gw = ugw0_[t] + e;
              v[e] = (gw >= 0 && gw < 64) ? base[gw] : 0.f;
            }
          }
        }
        if (uint_[t]) {
#pragma unroll
          for (int e = 0; e < 4; ++e)
            *(short*)(xsw + uwb0_[t] + e * XS_STRIDE) = f2bf(v[e]);
        } else {
#pragma unroll
          for (int e = 0; e < 4; ++e) {
            const int ww = 4 * uf4g_[t] + e - 3;
            if (ww >= 0 && ww < 18)
              *(short*)(xsw + (urow_[t] * 18 + ww) * XS_STRIDE + uic_[t] * 2) = f2bf(v[e]);
          }
        }
      }
    }
#pragma unroll
    for (int k = 0; k < 5; ++k) {
      if (actA[k]) {
        const f32x4v v = *(const f32x4v*)(wbase_b + preoff[k]);
#pragma unroll
        for (int e = 0; e < 4; ++e)
          *(short*)(smem + woff[k][e]) = f2bf(v[e]);
      }
    }
  }
  __syncthreads();

  // ---------------- K-loop: 16 chunks, ONE barrier each ----------------
  for (int cc = 0; cc < 16; ++cc) {
    char* Asr = smem + (cc & 1) * AS_SZ;
    char* xsr = smem + XS_BASE + (cc & 1) * XS_SZ;
    char* Asw = smem + ((cc + 1) & 1) * AS_SZ;
    char* xsw = smem + XS_BASE + ((cc + 1) & 1) * XS_SZ;
    const bool have = cc < 15;

    // issue x loads for chunk cc+1 (latency hides under MFMA)
    float xv[2][4];
#pragma unroll
    for (int t = 0; t < 2; ++t) {
#pragma unroll
      for (int e = 0; e < 4; ++e) xv[t][e] = 0.f;
      if (have && uact_[t] && urowok_[t]) {
        const float* base =
            x + (((size_t)(n * 256 + (cc + 1) * 16 + uic_[t])) * 64 + ugh_[t]) * 64;
        if (ual_[t]) {
          const f32x4v fv = *(const f32x4v*)(base + ugw0_[t]);
#pragma unroll
          for (int e = 0; e < 4; ++e) xv[t][e] = fv[e];
        } else {
#pragma unroll
          for (int e = 0; e < 4; ++e) {
            const int gw = ugw0_[t] + e;
            xv[t][e] = (gw >= 0 && gw < 64) ? base[gw] : 0.f;
          }
        }
      }
    }
    // issue w loads for chunk cc+1
    f32x4v wv[5];
#pragma unroll
    for (int k = 0; k < 5; ++k) {
      if (have && actA[k])
        wv[k] = *(const f32x4v*)(wbase_b + preoff[k] + (cc + 1) * 576);
    }

    // MFMA on chunk cc (swizzled A-frag reads), prioritized
    __builtin_amdgcn_s_setprio(1);
#pragma unroll
    for (int slot = 0; slot < 3; ++slot) {
#pragma unroll
      for (int s = 0; s < 4; ++s) {
        if (s < nkS[slot]) {
          const int kq = kqS[slot][s];
          const bf16x8 B  = *(const bf16x8*)(xsr + cellxS[slot][s] * XS_STRIDE + q * 16);
          const bf16x8 Aa = *(const bf16x8*)(Asr + kq * 2048 + swzb);
          const bf16x8 Ab = *(const bf16x8*)(Asr + kq * 2048 + 1024 + swzb);
          acc[slot][0] = __builtin_amdgcn_mfma_f32_32x32x16_bf16(Aa, B, acc[slot][0], 0, 0, 0);
          acc[slot][1] = __builtin_amdgcn_mfma_f32_32x32x16_bf16(Ab, B, acc[slot][1], 0, 0, 0);
        }
      }
    }
    __builtin_amdgcn_s_setprio(0);

    if (have) {
      // x writes
#pragma unroll
      for (int t = 0; t < 2; ++t) {
        if (uact_[t]) {
          if (uint_[t]) {
#pragma unroll
            for (int e = 0; e < 4; ++e)
              *(short*)(xsw + uwb0_[t] + e * XS_STRIDE) = f2bf(xv[t][e]);
          } else {
#pragma unroll
            for (int e = 0; e < 4; ++e) {
              const int ww = 4 * uf4g_[t] + e - 3;
              if (ww >= 0 && ww < 18)
                *(short*)(xsw + (urow_[t] * 18 + ww) * XS_STRIDE + uic_[t] * 2) = f2bf(xv[t][e]);
            }
          }
        }
      }
      // w writes (precomputed swizzled offsets)
#pragma unroll
      for (int k = 0; k < 5; ++k) {
        if (actA[k]) {
#pragma unroll
          for (int e = 0; e < 4; ++e)
            *(short*)(Asw + woff[k][e]) = f2bf(wv[k][e]);
        }
      }
    }
    __syncthreads();
  }

  // ---------------- epilogue: 2 phases (mf = oc-half), verbatim R15 ----------------
  short* hl = (short*)smem;
  const float kf4[4] = {0.25f, 0.75f, 0.75f, 0.25f};
#pragma unroll
  for (int mf = 0; mf < 2; ++mf) {
    if (mf) __syncthreads();
#pragma unroll
    for (int slot = 0; slot < 3; ++slot) {
      if (validS[slot]) {
#pragma unroll
        for (int e = 0; e < 16; ++e) {
          const int ocl = (e & 3) + 8 * (e >> 2) + 4 * q;
          hl[hbaseS[slot] + ocl * 200] = f2bf(acc[slot][mf][e]);
        }
      }
    }
    __syncthreads();
#pragma unroll
    for (int k = 0; k < 4; ++k) {
      const int v = tid + k * 512;
      const int g = v & 3;
      const int Yl = (v >> 2) & 15;
      const int ocl = v >> 6;
      float o[8];
#pragma unroll
      for (int xx = 0; xx < 8; ++xx) o[xx] = 0.f;
#pragma unroll
      for (int du = 0; du < 4; ++du) {
        const int ttp = Yl - 1 + du;
        const int py = ttp & 1;
        const int r = py ? ((Yl + du) >> 1) : (ttp >> 1);
        const int baseE = (py * 2) * 6400 + ocl * 200 + r * 20 + 4 * g;
        const int baseO = (py * 2 + 1) * 6400 + ocl * 200 + r * 20 + 4 * g;
        const short4v e0 = *(const short4v*)(hl + baseE);
        const short4v e1 = *(const short4v*)(hl + baseE + 4);
        const short4v o0 = *(const short4v*)(hl + baseO);
        const short4v o1 = *(const short4v*)(hl + baseO + 4);
        float E[8], O[8];
#pragma unroll
        for (int i = 0; i < 4; ++i) {
          E[i] = bf2f(e0[i]); E[i + 4] = bf2f(e1[i]);
          O[i] = bf2f(o0[i]); O[i + 4] = bf2f(o1[i]);
        }
        float rx[8];
        rx[0] = 0.25f*O[0] + 0.75f*E[0] + 0.75f*O[1] + 0.25f*E[1];
        rx[1] = 0.25f*E[0] + 0.75f*O[1] + 0.75f*E[1] + 0.25f*O[2];
        rx[2] = 0.25f*O[1] + 0.75f*E[1] + 0.75f*O[2] + 0.25f*E[2];
        rx[3] = 0.25f*E[1] + 0.75f*O[2] + 0.75f*E[2] + 0.25f*O[3];
        rx[4] = 0.25f*O[2] + 0.75f*E[2] + 0.75f*O[3] + 0.25f*E[3];
        rx[5] = 0.25f*E[2] + 0.75f*O[3] + 0.75f*E[3] + 0.25f*O[4];
        rx[6] = 0.25f*O[3] + 0.75f*E[3] + 0.75f*O[4] + 0.25f*E[4];
        rx[7] = 0.25f*E[3] + 0.75f*O[4] + 0.75f*E[4] + 0.25f*O[5];
        const float ky = kf4[du];
#pragma unroll
        for (int xx = 0; xx < 8; ++xx) o[xx] += ky * rx[xx];
      }
      const int oc = octile * 64 + mf * 32 + ocl;
      const int Y = atile * 16 + Yl;
      const int X0 = btile * 32 + g * 8;
      float* op = out + (((size_t)(n * 256 + oc)) * 128 + Y) * 128 + X0;
      f32x4v v0, v1;
      v0[0] = o[0]; v0[1] = o[1]; v0[2] = o[2]; v0[3] = o[3];
      v1[0] = o[4]; v1[1] = o[5]; v1[2] = o[6]; v1[3] = o[7];
      *(f32x4v*)op = v0;
      *(f32x4v*)(op + 4) = v1;
    }
  }
}

extern "C" void kernel_launch(void* const* d_in, const int* in_sizes, int n_in,
                              void* d_out, int out_size, void* d_ws, size_t ws_size,
                              hipStream_t stream) {
  (void)in_sizes; (void)n_in; (void)out_size; (void)d_ws; (void)ws_size;
  const float* x = (const float*)d_in[0];
  const float* w = (const float*)d_in[1];
  float* out = (float*)d_out;
  // grid = 4 octiles x 4 n x 32 spatial = 512 blocks, 512 threads
  hipLaunchKernelGGL(fir_up_v16, dim3(512), dim3(512), 0, stream, x, w, out);
}

// Round 18
// 85.314 us; speedup vs baseline: 1.2137x; 1.2137x over previous
//
#include <hip/hip_runtime.h>
#include <hip/hip_bf16.h>

// FirUpsample R17 = R15 pipeline (93us family best: single-barrier dbuf,
// native cvt, interior fast path, setprio) + PLANE-GROUPED wave partition
// (R8/R9/R10-verified tables): each wave owns fgs of ONE plane, so one
// A-fragment pair feeds up to 4 B-frags -> LDS b128 reads/chunk 162 -> 94
// (-42%), MFMA 108 -> 100. R16's A-swizzle reverted (wave A-reads cover 64
// distinct slots = port minimum already; swizzle only hurt the write side).
// acc[4][2] (<=128 AGPR + ~88 VGPR = 216 <= 256/lane at 2 waves/SIMD).
// Math (verified R5-R16, absmax 0.015625): h = dilated conv3x3 as 4 parity-
// plane GEMMs (10.3 G MAC); separable 4-tap FIR epilogue from LDS.

typedef short short2v __attribute__((ext_vector_type(2)));
typedef short bf16x8 __attribute__((ext_vector_type(8)));
typedef short short4v __attribute__((ext_vector_type(4)));
typedef float f32x2v __attribute__((ext_vector_type(2)));
typedef float f32x16 __attribute__((ext_vector_type(16)));
typedef float f32x4v __attribute__((ext_vector_type(4)));

static __device__ __forceinline__ short f2bf(float f) {
  __hip_bfloat16 h = __float2bfloat16(f);
  union { __hip_bfloat16 h; short s; } u; u.h = h;
  return u.s;
}
static __device__ __forceinline__ float bf2f(short s) {
  union { unsigned u; float f; } v; v.u = ((unsigned)(unsigned short)s) << 16;
  return v.f;
}

#define AS_SZ 18432           // one As buffer: [9 kq][64 oc][16 ic] bf16
#define XS_BASE 36864         // 2*AS_SZ
#define XS_SZ 8640            // one xs buffer: [180 cells][48 B]
#define XS_STRIDE 48

__global__ __launch_bounds__(512, 2)
void fir_up_v17(const float* __restrict__ x, const float* __restrict__ w,
                float* __restrict__ out) {
  __shared__ __align__(16) char smem[54144];

  const int bid = blockIdx.x;
  const int wg = (bid & 7) * 64 + (bid >> 3);
  const int octile = wg >> 7;        // 0..3 (64 oc each)
  const int n = (wg >> 5) & 3;
  const int sp = wg & 31;
  const int atile = sp >> 2;
  const int btile = sp & 3;
  const int A0 = atile * 8, B0 = btile * 16;

  const int tid = threadIdx.x;
  const int wid = tid >> 6;
  const int lane = tid & 63;
  const int l31 = lane & 31, q = lane >> 5;

  // ---- plane geometry + PLANE-GROUPED partition (R8/R9/R10-verified) ----
  const int COLSt[4]  = {17, 18, 17, 18};
  const int CELLSt[4] = {153, 162, 170, 180};
  const int NKt[4]    = {4, 2, 2, 1};
  const int KQt[4][4] = {{0,2,6,8},{1,7,7,7},{3,5,5,5},{4,4,4,4}};
  const int DYt[4][4] = {{0,0,1,1},{0,1,1,1},{0,0,0,0},{0,0,0,0}};
  const int DXt[4][4] = {{0,1,0,1},{0,0,0,0},{0,1,1,1},{0,0,0,0}};
  // waves: w0 p0{0,1} w1 p0{2,3} w2 p0{4}+p3{4,5} w3 p1{0,1,2} w4 p1{3,4,5}
  //        w5 p2{0,1,2} w6 p2{3,4,5} w7 p3{0,1,2,3}
  const int SEG0P[8]   = {0,0,0,1,1,2,2,3};
  const int SEG0FGB[8] = {0,2,4,0,3,0,3,0};
  const int SEG0NFG[8] = {2,2,1,3,3,3,3,4};

  const int p0w = SEG0P[wid];
  const int nk0 = NKt[p0w];
  const int nfg0 = SEG0NFG[wid];
  int aoff0[4];
#pragma unroll
  for (int s = 0; s < 4; ++s)
    aoff0[s] = KQt[p0w][s] * 2048 + l31 * 32 + q * 16;
  int boff0[4][4], valid0[4], hbase0[4];
#pragma unroll
  for (int fg = 0; fg < 4; ++fg) {
    const int cellraw = (SEG0FGB[wid] + fg) * 32 + l31;
    const int valid = cellraw < CELLSt[p0w];
    const int cell = valid ? cellraw : 0;
    const int cols = COLSt[p0w];
    const int r = cell / cols;
    const int c = cell - r * cols;
    valid0[fg] = valid;
    hbase0[fg] = p0w * 6400 + r * 20 + c;
#pragma unroll
    for (int s = 0; s < 4; ++s) {
      const int bc = (r + DYt[p0w][s]) * 18 + (c + DXt[p0w][s]);
      boff0[fg][s] = bc * XS_STRIDE + q * 16;
    }
  }
  // w2's second segment: p3 (kq=4, dy=dx=0), fgs {4,5} -> acc[1],acc[2]
  const int aoff1 = 4 * 2048 + l31 * 32 + q * 16;
  int boff1[2], valid1[2], hbase1[2];
#pragma unroll
  for (int j = 0; j < 2; ++j) {
    const int cellraw = (4 + j) * 32 + l31;
    const int valid = cellraw < 180;
    const int cell = valid ? cellraw : 0;
    const int r = cell / 18;
    const int c = cell - r * 18;
    valid1[j] = valid;
    hbase1[j] = 3 * 6400 + r * 20 + c;
    boff1[j] = cell * XS_STRIDE + q * 16;
  }

  f32x16 acc[4][2];
#pragma unroll
  for (int fg = 0; fg < 4; ++fg)
#pragma unroll
    for (int mf = 0; mf < 2; ++mf)
#pragma unroll
      for (int e = 0; e < 16; ++e) acc[fg][mf][e] = 0.f;

  // ---- staging unit decode (verbatim R15) ----
  const int ocA = tid >> 3, icp = tid & 7;
  const float* wA = w + (size_t)(octile * 64 + ocA) * 2304 + icp * 18;
  int uic_[2], urow_[2], uf4g_[2], ugh_[2], ugw0_[2], uwb0_[2];
  bool uact_[2], urowok_[2], ual_[2], uint_[2];
#pragma unroll
  for (int t = 0; t < 2; ++t) {
    const int u = tid + t * 512;
    uact_[t] = u < 960;
    const int uu = uact_[t] ? u : 0;
    uic_[t] = uu / 60;
    const int rem = uu - uic_[t] * 60;
    urow_[t] = rem / 6;
    uf4g_[t] = rem - urow_[t] * 6;
    ugh_[t] = A0 - 1 + urow_[t];
    urowok_[t] = (ugh_[t] >= 0) & (ugh_[t] < 64);
    ugw0_[t] = B0 - 4 + 4 * uf4g_[t];
    ual_[t] = (ugw0_[t] >= 0) & (ugw0_[t] <= 60);
    uint_[t] = (uf4g_[t] >= 1) & (uf4g_[t] <= 4);
    uwb0_[t] = (urow_[t] * 18 + (4 * uf4g_[t] - 3)) * XS_STRIDE + uic_[t] * 2;
  }

  // ---- prologue: stage chunk 0 into buffers 0 (verbatim R15) ----
  {
    char* xsw = smem + XS_BASE;
#pragma unroll
    for (int t = 0; t < 2; ++t) {
      if (uact_[t]) {
        float v[4] = {0.f, 0.f, 0.f, 0.f};
        if (urowok_[t]) {
          const float* base = x + (((size_t)(n * 256 + uic_[t])) * 64 + ugh_[t]) * 64;
          if (ual_[t]) {
            const f32x4v fv = *(const f32x4v*)(base + ugw0_[t]);
#pragma unroll
            for (int e = 0; e < 4; ++e) v[e] = fv[e];
          } else {
#pragma unroll
            for (int e = 0; e < 4; ++e) {
              const int gw = ugw0_[t] + e;
              v[e] = (gw >= 0 && gw < 64) ? base[gw] : 0.f;
            }
          }
        }
        if (uint_[t]) {
#pragma unroll
          for (int e = 0; e < 4; ++e)
            *(short*)(xsw + uwb0_[t] + e * XS_STRIDE) = f2bf(v[e]);
        } else {
#pragma unroll
          for (int e = 0; e < 4; ++e) {
            const int ww = 4 * uf4g_[t] + e - 3;
            if (ww >= 0 && ww < 18)
              *(short*)(xsw + (urow_[t] * 18 + ww) * XS_STRIDE + uic_[t] * 2) = f2bf(v[e]);
          }
        }
      }
    }
    float f18[18];
#pragma unroll
    for (int j = 0; j < 9; ++j)
      *(f32x2v*)&f18[2 * j] = *(const f32x2v*)(wA + 2 * j);
#pragma unroll
    for (int kq = 0; kq < 9; ++kq) {
      short2v pk;
      pk[0] = f2bf(f18[kq]);
      pk[1] = f2bf(f18[kq + 9]);
      *(short2v*)(smem + kq * 2048 + ocA * 32 + icp * 4) = pk;
    }
  }
  __syncthreads();

  // ---------------- K-loop: 16 chunks, ONE barrier each ----------------
  for (int cc = 0; cc < 16; ++cc) {
    char* Asr = smem + (cc & 1) * AS_SZ;
    char* xsr = smem + XS_BASE + (cc & 1) * XS_SZ;
    char* Asw = smem + ((cc + 1) & 1) * AS_SZ;
    char* xsw = smem + XS_BASE + ((cc + 1) & 1) * XS_SZ;
    const bool have = cc < 15;

    // issue x loads for chunk cc+1 (latency hides under MFMA)
    float xv[2][4];
#pragma unroll
    for (int t = 0; t < 2; ++t) {
#pragma unroll
      for (int e = 0; e < 4; ++e) xv[t][e] = 0.f;
      if (have && uact_[t] && urowok_[t]) {
        const float* base =
            x + (((size_t)(n * 256 + (cc + 1) * 16 + uic_[t])) * 64 + ugh_[t]) * 64;
        if (ual_[t]) {
          const f32x4v fv = *(const f32x4v*)(base + ugw0_[t]);
#pragma unroll
          for (int e = 0; e < 4; ++e) xv[t][e] = fv[e];
        } else {
#pragma unroll
          for (int e = 0; e < 4; ++e) {
            const int gw = ugw0_[t] + e;
            xv[t][e] = (gw >= 0 && gw < 64) ? base[gw] : 0.f;
          }
        }
      }
    }

    // MFMA on chunk cc: plane-grouped (A-pair shared across fgs), prioritized
    __builtin_amdgcn_s_setprio(1);
#pragma unroll
    for (int s = 0; s < 4; ++s) {
      if (s < nk0) {
        const bf16x8 Aa = *(const bf16x8*)(Asr + aoff0[s]);
        const bf16x8 Ab = *(const bf16x8*)(Asr + aoff0[s] + 1024);
#pragma unroll
        for (int fg = 0; fg < 4; ++fg) {
          if (fg < nfg0) {
            const bf16x8 B = *(const bf16x8*)(xsr + boff0[fg][s]);
            acc[fg][0] = __builtin_amdgcn_mfma_f32_32x32x16_bf16(Aa, B, acc[fg][0], 0, 0, 0);
            acc[fg][1] = __builtin_amdgcn_mfma_f32_32x32x16_bf16(Ab, B, acc[fg][1], 0, 0, 0);
          }
        }
      }
    }
    if (wid == 2) {
      const bf16x8 Aa = *(const bf16x8*)(Asr + aoff1);
      const bf16x8 Ab = *(const bf16x8*)(Asr + aoff1 + 1024);
#pragma unroll
      for (int j = 0; j < 2; ++j) {
        const bf16x8 B = *(const bf16x8*)(xsr + boff1[j]);
        acc[1 + j][0] = __builtin_amdgcn_mfma_f32_32x32x16_bf16(Aa, B, acc[1 + j][0], 0, 0, 0);
        acc[1 + j][1] = __builtin_amdgcn_mfma_f32_32x32x16_bf16(Ab, B, acc[1 + j][1], 0, 0, 0);
      }
    }
    __builtin_amdgcn_s_setprio(0);

    if (have) {
#pragma unroll
      for (int t = 0; t < 2; ++t) {
        if (uact_[t]) {
          if (uint_[t]) {
#pragma unroll
            for (int e = 0; e < 4; ++e)
              *(short*)(xsw + uwb0_[t] + e * XS_STRIDE) = f2bf(xv[t][e]);
          } else {
#pragma unroll
            for (int e = 0; e < 4; ++e) {
              const int ww = 4 * uf4g_[t] + e - 3;
              if (ww >= 0 && ww < 18)
                *(short*)(xsw + (urow_[t] * 18 + ww) * XS_STRIDE + uic_[t] * 2) = f2bf(xv[t][e]);
            }
          }
        }
      }
      float f18[18];
      const float* wp = wA + (cc + 1) * 144;
#pragma unroll
      for (int j = 0; j < 9; ++j)
        *(f32x2v*)&f18[2 * j] = *(const f32x2v*)(wp + 2 * j);
#pragma unroll
      for (int kq = 0; kq < 9; ++kq) {
        short2v pk;
        pk[0] = f2bf(f18[kq]);
        pk[1] = f2bf(f18[kq + 9]);
        *(short2v*)(Asw + kq * 2048 + ocA * 32 + icp * 4) = pk;
      }
    }
    __syncthreads();
  }

  // ---------------- epilogue: 2 phases (mf = oc-half) ----------------
  short* hl = (short*)smem;
  const float kf4[4] = {0.25f, 0.75f, 0.75f, 0.25f};
#pragma unroll
  for (int mf = 0; mf < 2; ++mf) {
    if (mf) __syncthreads();
#pragma unroll
    for (int fg = 0; fg < 4; ++fg) {
      if (fg < nfg0 && valid0[fg]) {
#pragma unroll
        for (int e = 0; e < 16; ++e) {
          const int ocl = (e & 3) + 8 * (e >> 2) + 4 * q;
          hl[hbase0[fg] + ocl * 200] = f2bf(acc[fg][mf][e]);
        }
      }
    }
    if (wid == 2) {
#pragma unroll
      for (int j = 0; j < 2; ++j) {
        if (valid1[j]) {
#pragma unroll
          for (int e = 0; e < 16; ++e) {
            const int ocl = (e & 3) + 8 * (e >> 2) + 4 * q;
            hl[hbase1[j] + ocl * 200] = f2bf(acc[1 + j][mf][e]);
          }
        }
      }
    }
    __syncthreads();
#pragma unroll
    for (int k = 0; k < 4; ++k) {
      const int v = tid + k * 512;
      const int g = v & 3;
      const int Yl = (v >> 2) & 15;
      const int ocl = v >> 6;
      float o[8];
#pragma unroll
      for (int xx = 0; xx < 8; ++xx) o[xx] = 0.f;
#pragma unroll
      for (int du = 0; du < 4; ++du) {
        const int ttp = Yl - 1 + du;
        const int py = ttp & 1;
        const int r = py ? ((Yl + du) >> 1) : (ttp >> 1);
        const int baseE = (py * 2) * 6400 + ocl * 200 + r * 20 + 4 * g;
        const int baseO = (py * 2 + 1) * 6400 + ocl * 200 + r * 20 + 4 * g;
        const short4v e0 = *(const short4v*)(hl + baseE);
        const short4v e1 = *(const short4v*)(hl + baseE + 4);
        const short4v o0 = *(const short4v*)(hl + baseO);
        const short4v o1 = *(const short4v*)(hl + baseO + 4);
        float E[8], O[8];
#pragma unroll
        for (int i = 0; i < 4; ++i) {
          E[i] = bf2f(e0[i]); E[i + 4] = bf2f(e1[i]);
          O[i] = bf2f(o0[i]); O[i + 4] = bf2f(o1[i]);
        }
        float rx[8];
        rx[0] = 0.25f*O[0] + 0.75f*E[0] + 0.75f*O[1] + 0.25f*E[1];
        rx[1] = 0.25f*E[0] + 0.75f*O[1] + 0.75f*E[1] + 0.25f*O[2];
        rx[2] = 0.25f*O[1] + 0.75f*E[1] + 0.75f*O[2] + 0.25f*E[2];
        rx[3] = 0.25f*E[1] + 0.75f*O[2] + 0.75f*E[2] + 0.25f*O[3];
        rx[4] = 0.25f*O[2] + 0.75f*E[2] + 0.75f*O[3] + 0.25f*E[3];
        rx[5] = 0.25f*E[2] + 0.75f*O[3] + 0.75f*E[3] + 0.25f*O[4];
        rx[6] = 0.25f*O[3] + 0.75f*E[3] + 0.75f*O[4] + 0.25f*E[4];
        rx[7] = 0.25f*E[3] + 0.75f*O[4] + 0.75f*E[4] + 0.25f*O[5];
        const float ky = kf4[du];
#pragma unroll
        for (int xx = 0; xx < 8; ++xx) o[xx] += ky * rx[xx];
      }
      const int oc = octile * 64 + mf * 32 + ocl;
      const int Y = atile * 16 + Yl;
      const int X0 = btile * 32 + g * 8;
      float* op = out + (((size_t)(n * 256 + oc)) * 128 + Y) * 128 + X0;
      f32x4v v0, v1;
      v0[0] = o[0]; v0[1] = o[1]; v0[2] = o[2]; v0[3] = o[3];
      v1[0] = o[4]; v1[1] = o[5]; v1[2] = o[6]; v1[3] = o[7];
      *(f32x4v*)op = v0;
      *(f32x4v*)(op + 4) = v1;
    }
  }
}

extern "C" void kernel_launch(void* const* d_in, const int* in_sizes, int n_in,
                              void* d_out, int out_size, void* d_ws, size_t ws_size,
                              hipStream_t stream) {
  (void)in_sizes; (void)n_in; (void)out_size; (void)d_ws; (void)ws_size;
  const float* x = (const float*)d_in[0];
  const float* w = (const float*)d_in[1];
  float* out = (float*)d_out;
  // grid = 4 octiles x 4 n x 32 spatial = 512 blocks, 512 threads
  hipLaunchKernelGGL(fir_up_v17, dim3(512), dim3(512), 0, stream, x, w, out);
}

// Round 19
// 81.590 us; speedup vs baseline: 1.2691x; 1.0456x over previous
//
#include <hip/hip_runtime.h>
#include <hip/hip_bf16.h>

// FirUpsample R18 = R17 (85.3us: plane-grouped A-reuse, single-barrier dbuf,
// native cvt, setprio) + 32-ic K-chunks: 8 barriers instead of 16 -- each
// barrier/latency drain now amortized over a 2x-long MFMA cluster.
// Enablers: acc[3][2] = 96 AGPR (p3-fg3 moved w7->w0 as hardcoded seg1, all
// acc indices compile-time) -> VGPR budget 160 absorbs doubled held regs;
// 80-B padded LDS rows (As and xs): slot walk l31*5+s covers all 8 bank
// quads -> conflict-free b128 reads (64-B stride would be 16-way).
// Math (verified R5-R17, absmax 0.015625): h = dilated conv3x3 as 4 parity-
// plane GEMMs (10.3 G MAC); separable 4-tap FIR epilogue from LDS.
// Summation order per output unchanged -> bit-identical result expected.

typedef short bf16x4v __attribute__((ext_vector_type(4)));
typedef short bf16x8 __attribute__((ext_vector_type(8)));
typedef short short4v __attribute__((ext_vector_type(4)));
typedef float f32x16 __attribute__((ext_vector_type(16)));
typedef float f32x4v __attribute__((ext_vector_type(4)));

static __device__ __forceinline__ short f2bf(float f) {
  __hip_bfloat16 h = __float2bfloat16(f);
  union { __hip_bfloat16 h; short s; } u; u.h = h;
  return u.s;
}
static __device__ __forceinline__ float bf2f(short s) {
  union { unsigned u; float f; } v; v.u = ((unsigned)(unsigned short)s) << 16;
  return v.f;
}

#define AS_SZ 46080       // one As buffer: [9 kq][64 oc][80 B] (32 ic + 16B pad)
#define KQ_PLANE 5120     // 64 oc * 80 B
#define AB_OFF 2560       // +32 oc rows
#define XS_BASE 92160     // 2*AS_SZ
#define XS_SZ 14400       // one xs buffer: [180 cells][80 B]
#define XS_STRIDE 80

__global__ __launch_bounds__(512, 2)
void fir_up_v18(const float* __restrict__ x, const float* __restrict__ w,
                float* __restrict__ out) {
  __shared__ __align__(16) char smem[120960];

  const int bid = blockIdx.x;
  const int wg = (bid & 7) * 64 + (bid >> 3);
  const int octile = wg >> 7;        // 0..3 (64 oc each)
  const int n = (wg >> 5) & 3;
  const int sp = wg & 31;
  const int atile = sp >> 2;
  const int btile = sp & 3;
  const int A0 = atile * 8, B0 = btile * 16;

  const int tid = threadIdx.x;
  const int wid = tid >> 6;
  const int lane = tid & 63;
  const int l31 = lane & 31, q = lane >> 5;

  // ---- plane geometry + plane-grouped partition (max 3 fgs/wave) ----
  const int COLSt[4]  = {17, 18, 17, 18};
  const int CELLSt[4] = {153, 162, 170, 180};
  const int NKt[4]    = {4, 2, 2, 1};
  const int KQt[4][4] = {{0,2,6,8},{1,7,7,7},{3,5,5,5},{4,4,4,4}};
  const int DYt[4][4] = {{0,0,1,1},{0,1,1,1},{0,0,0,0},{0,0,0,0}};
  const int DXt[4][4] = {{0,1,0,1},{0,0,0,0},{0,1,1,1},{0,0,0,0}};
  // seg0: w0 p0{0,1} w1 p0{2,3} w2 p0{4} w3 p1{0,1,2} w4 p1{3,4,5}
  //       w5 p2{0,1,2} w6 p2{3,4,5} w7 p3{0,1,2}
  // seg1 (hardcoded): w0 += p3{3} -> acc[2];  w2 += p3{4,5} -> acc[1],acc[2]
  const int SEG0P[8]   = {0,0,0,1,1,2,2,3};
  const int SEG0FGB[8] = {0,2,4,0,3,0,3,0};
  const int SEG0NFG[8] = {2,2,1,3,3,3,3,3};

  const int p0w = SEG0P[wid];
  const int nk0 = NKt[p0w];
  const int nfg0 = SEG0NFG[wid];
  int aoff0[4];
#pragma unroll
  for (int s = 0; s < 4; ++s)
    aoff0[s] = KQt[p0w][s] * KQ_PLANE + l31 * 80 + q * 16;
  int boff0[3][4], valid0[3], hbase0[3];
#pragma unroll
  for (int fg = 0; fg < 3; ++fg) {
    const int cellraw = (SEG0FGB[wid] + fg) * 32 + l31;
    const int valid = cellraw < CELLSt[p0w];
    const int cell = valid ? cellraw : 0;
    const int cols = COLSt[p0w];
    const int r = cell / cols;
    const int c = cell - r * cols;
    valid0[fg] = valid;
    hbase0[fg] = p0w * 6400 + r * 20 + c;
#pragma unroll
    for (int s = 0; s < 4; ++s) {
      const int bc = (r + DYt[p0w][s]) * 18 + (c + DXt[p0w][s]);
      boff0[fg][s] = bc * XS_STRIDE + q * 16;
    }
  }
  // seg1 geometry (p3: kq=4, dy=dx=0)
  const int aoff1 = 4 * KQ_PLANE + l31 * 80 + q * 16;
  // w0: fg3 -> cells 96+l31 (always valid)
  int boffW0, hbaseW0;
  {
    const int cell = 96 + l31;
    const int r = cell / 18, c = cell - r * 18;
    hbaseW0 = 3 * 6400 + r * 20 + c;
    boffW0 = cell * XS_STRIDE + q * 16;
  }
  // w2: fgs {4,5} -> cells 128+l31, 160+l31 (fg5 partial)
  int boff1[2], valid1[2], hbase1[2];
#pragma unroll
  for (int j = 0; j < 2; ++j) {
    const int cellraw = (4 + j) * 32 + l31;
    const int valid = cellraw < 180;
    const int cell = valid ? cellraw : 0;
    const int r = cell / 18, c = cell - r * 18;
    valid1[j] = valid;
    hbase1[j] = 3 * 6400 + r * 20 + c;
    boff1[j] = cell * XS_STRIDE + q * 16;
  }

  f32x16 acc[3][2];
#pragma unroll
  for (int fg = 0; fg < 3; ++fg)
#pragma unroll
    for (int mf = 0; mf < 2; ++mf)
#pragma unroll
      for (int e = 0; e < 16; ++e) acc[fg][mf][e] = 0.f;

  // ---- staging unit decode ----
  // A: unit = (ocA 0..63, icq 0..7): 36 consecutive floats = 4 ic x 9 kq
  const int ocA = tid >> 3, icq = tid & 7;
  const float* wA = w + (size_t)(octile * 64 + ocA) * 2304 + icq * 36;
  const int awb = ocA * 80 + icq * 8;   // + kq*KQ_PLANE at write
  // x: 1920 units, u = ic*60 + row*6 + f4g (f4g lane-minor, coalesced)
  int uic_[4], urow_[4], uf4g_[4], ugh_[4], ugw0_[4], uwb0_[4];
  bool uact_[4], urowok_[4], ual_[4], uint_[4];
#pragma unroll
  for (int t = 0; t < 4; ++t) {
    const int u = tid + t * 512;
    uact_[t] = u < 1920;
    const int uu = uact_[t] ? u : 0;
    uic_[t] = uu / 60;
    const int rem = uu - uic_[t] * 60;
    urow_[t] = rem / 6;
    uf4g_[t] = rem - urow_[t] * 6;
    ugh_[t] = A0 - 1 + urow_[t];
    urowok_[t] = (ugh_[t] >= 0) & (ugh_[t] < 64);
    ugw0_[t] = B0 - 4 + 4 * uf4g_[t];
    ual_[t] = (ugw0_[t] >= 0) & (ugw0_[t] <= 60);
    uint_[t] = (uf4g_[t] >= 1) & (uf4g_[t] <= 4);
    uwb0_[t] = (urow_[t] * 18 + (4 * uf4g_[t] - 3)) * XS_STRIDE + uic_[t] * 2;
  }

  // ---- prologue: stage chunk 0 into buffers 0 ----
  {
    char* xsw = smem + XS_BASE;
#pragma unroll
    for (int t = 0; t < 4; ++t) {
      if (uact_[t]) {
        float v[4] = {0.f, 0.f, 0.f, 0.f};
        if (urowok_[t]) {
          const float* base = x + (((size_t)(n * 256 + uic_[t])) * 64 + ugh_[t]) * 64;
          if (ual_[t]) {
            const f32x4v fv = *(const f32x4v*)(base + ugw0_[t]);
#pragma unroll
            for (int e = 0; e < 4; ++e) v[e] = fv[e];
          } else {
#pragma unroll
            for (int e = 0; e < 4; ++e) {
              const int gw = ugw0_[t] + e;
              v[e] = (gw >= 0 && gw < 64) ? base[gw] : 0.f;
            }
          }
        }
        if (uint_[t]) {
#pragma unroll
          for (int e = 0; e < 4; ++e)
            *(short*)(xsw + uwb0_[t] + e * XS_STRIDE) = f2bf(v[e]);
        } else {
#pragma unroll
          for (int e = 0; e < 4; ++e) {
            const int ww = 4 * uf4g_[t] + e - 3;
            if (ww >= 0 && ww < 18)
              *(short*)(xsw + (urow_[t] * 18 + ww) * XS_STRIDE + uic_[t] * 2) = f2bf(v[e]);
          }
        }
      }
    }
    float f36[36];
#pragma unroll
    for (int j = 0; j < 9; ++j)
      *(f32x4v*)&f36[4 * j] = *(const f32x4v*)(wA + 4 * j);
#pragma unroll
    for (int kq = 0; kq < 9; ++kq) {
      bf16x4v pk;
#pragma unroll
      for (int v = 0; v < 4; ++v) pk[v] = f2bf(f36[v * 9 + kq]);
      *(bf16x4v*)(smem + kq * KQ_PLANE + awb) = pk;
    }
  }
  __syncthreads();

  // ---------------- K-loop: 8 chunks of 32 ic, ONE barrier each ----------------
  for (int cc = 0; cc < 8; ++cc) {
    char* Asr = smem + (cc & 1) * AS_SZ;
    char* xsr = smem + XS_BASE + (cc & 1) * XS_SZ;
    char* Asw = smem + ((cc + 1) & 1) * AS_SZ;
    char* xsw = smem + XS_BASE + ((cc + 1) & 1) * XS_SZ;
    const bool have = cc < 7;

    // issue x loads for chunk cc+1 (latency hides under MFMA)
    float xv[4][4];
#pragma unroll
    for (int t = 0; t < 4; ++t) {
#pragma unroll
      for (int e = 0; e < 4; ++e) xv[t][e] = 0.f;
      if (have && uact_[t] && urowok_[t]) {
        const float* base =
            x + (((size_t)(n * 256 + (cc + 1) * 32 + uic_[t])) * 64 + ugh_[t]) * 64;
        if (ual_[t]) {
          const f32x4v fv = *(const f32x4v*)(base + ugw0_[t]);
#pragma unroll
          for (int e = 0; e < 4; ++e) xv[t][e] = fv[e];
        } else {
#pragma unroll
          for (int e = 0; e < 4; ++e) {
            const int gw = ugw0_[t] + e;
            xv[t][e] = (gw >= 0 && gw < 64) ? base[gw] : 0.f;
          }
        }
      }
    }
    // issue w loads for chunk cc+1 (L2-resident)
    f32x4v wv[9];
#pragma unroll
    for (int j = 0; j < 9; ++j) {
      if (have) wv[j] = *(const f32x4v*)(wA + (cc + 1) * 288 + 4 * j);
    }

    // MFMA on chunk cc: plane-grouped, 2 ic-halves per kq, prioritized
    __builtin_amdgcn_s_setprio(1);
#pragma unroll
    for (int s = 0; s < 4; ++s) {
      if (s < nk0) {
#pragma unroll
        for (int h = 0; h < 2; ++h) {
          const bf16x8 Aa = *(const bf16x8*)(Asr + aoff0[s] + h * 32);
          const bf16x8 Ab = *(const bf16x8*)(Asr + aoff0[s] + h * 32 + AB_OFF);
#pragma unroll
          for (int fg = 0; fg < 3; ++fg) {
            if (fg < nfg0) {
              const bf16x8 B = *(const bf16x8*)(xsr + boff0[fg][s] + h * 32);
              acc[fg][0] = __builtin_amdgcn_mfma_f32_32x32x16_bf16(Aa, B, acc[fg][0], 0, 0, 0);
              acc[fg][1] = __builtin_amdgcn_mfma_f32_32x32x16_bf16(Ab, B, acc[fg][1], 0, 0, 0);
            }
          }
        }
      }
    }
    if (wid == 0) {
#pragma unroll
      for (int h = 0; h < 2; ++h) {
        const bf16x8 Aa = *(const bf16x8*)(Asr + aoff1 + h * 32);
        const bf16x8 Ab = *(const bf16x8*)(Asr + aoff1 + h * 32 + AB_OFF);
        const bf16x8 B = *(const bf16x8*)(xsr + boffW0 + h * 32);
        acc[2][0] = __builtin_amdgcn_mfma_f32_32x32x16_bf16(Aa, B, acc[2][0], 0, 0, 0);
        acc[2][1] = __builtin_amdgcn_mfma_f32_32x32x16_bf16(Ab, B, acc[2][1], 0, 0, 0);
      }
    }
    if (wid == 2) {
#pragma unroll
      for (int h = 0; h < 2; ++h) {
        const bf16x8 Aa = *(const bf16x8*)(Asr + aoff1 + h * 32);
        const bf16x8 Ab = *(const bf16x8*)(Asr + aoff1 + h * 32 + AB_OFF);
#pragma unroll
        for (int j = 0; j < 2; ++j) {
          const bf16x8 B = *(const bf16x8*)(xsr + boff1[j] + h * 32);
          acc[1 + j][0] = __builtin_amdgcn_mfma_f32_32x32x16_bf16(Aa, B, acc[1 + j][0], 0, 0, 0);
          acc[1 + j][1] = __builtin_amdgcn_mfma_f32_32x32x16_bf16(Ab, B, acc[1 + j][1], 0, 0, 0);
        }
      }
    }
    __builtin_amdgcn_s_setprio(0);

    if (have) {
      // x writes
#pragma unroll
      for (int t = 0; t < 4; ++t) {
        if (uact_[t]) {
          if (uint_[t]) {
#pragma unroll
            for (int e = 0; e < 4; ++e)
              *(short*)(xsw + uwb0_[t] + e * XS_STRIDE) = f2bf(xv[t][e]);
          } else {
#pragma unroll
            for (int e = 0; e < 4; ++e) {
              const int ww = 4 * uf4g_[t] + e - 3;
              if (ww >= 0 && ww < 18)
                *(short*)(xsw + (urow_[t] * 18 + ww) * XS_STRIDE + uic_[t] * 2) = f2bf(xv[t][e]);
            }
          }
        }
      }
      // w writes
#pragma unroll
      for (int kq = 0; kq < 9; ++kq) {
        bf16x4v pk;
#pragma unroll
        for (int v = 0; v < 4; ++v) pk[v] = f2bf(wv[v & 1 ? (v == 1 ? 2 : 6) : (v == 0 ? 0 : 4)][0]);
        // NOTE: the above would be wrong -- use direct indexing instead:
        (void)pk;
        bf16x4v pk2;
#pragma unroll
        for (int v = 0; v < 4; ++v) {
          const int flat = v * 9 + kq;        // float index within 36
          pk2[v] = f2bf(wv[flat >> 2][flat & 3]);
        }
        *(bf16x4v*)(Asw + kq * KQ_PLANE + awb) = pk2;
      }
    }
    __syncthreads();
  }

  // ---------------- epilogue: 2 phases (mf = oc-half) ----------------
  short* hl = (short*)smem;
  const float kf4[4] = {0.25f, 0.75f, 0.75f, 0.25f};
#pragma unroll
  for (int mf = 0; mf < 2; ++mf) {
    if (mf) __syncthreads();
#pragma unroll
    for (int fg = 0; fg < 3; ++fg) {
      if (fg < nfg0 && valid0[fg]) {
#pragma unroll
        for (int e = 0; e < 16; ++e) {
          const int ocl = (e & 3) + 8 * (e >> 2) + 4 * q;
          hl[hbase0[fg] + ocl * 200] = f2bf(acc[fg][mf][e]);
        }
      }
    }
    if (wid == 0) {
#pragma unroll
      for (int e = 0; e < 16; ++e) {
        const int ocl = (e & 3) + 8 * (e >> 2) + 4 * q;
        hl[hbaseW0 + ocl * 200] = f2bf(acc[2][mf][e]);
      }
    }
    if (wid == 2) {
#pragma unroll
      for (int j = 0; j < 2; ++j) {
        if (valid1[j]) {
#pragma unroll
          for (int e = 0; e < 16; ++e) {
            const int ocl = (e & 3) + 8 * (e >> 2) + 4 * q;
            hl[hbase1[j] + ocl * 200] = f2bf(acc[1 + j][mf][e]);
          }
        }
      }
    }
    __syncthreads();
#pragma unroll
    for (int k = 0; k < 4; ++k) {
      const int v = tid + k * 512;
      const int g = v & 3;
      const int Yl = (v >> 2) & 15;
      const int ocl = v >> 6;
      float o[8];
#pragma unroll
      for (int xx = 0; xx < 8; ++xx) o[xx] = 0.f;
#pragma unroll
      for (int du = 0; du < 4; ++du) {
        const int ttp = Yl - 1 + du;
        const int py = ttp & 1;
        const int r = py ? ((Yl + du) >> 1) : (ttp >> 1);
        const int baseE = (py * 2) * 6400 + ocl * 200 + r * 20 + 4 * g;
        const int baseO = (py * 2 + 1) * 6400 + ocl * 200 + r * 20 + 4 * g;
        const short4v e0 = *(const short4v*)(hl + baseE);
        const short4v e1 = *(const short4v*)(hl + baseE + 4);
        const short4v o0 = *(const short4v*)(hl + baseO);
        const short4v o1 = *(const short4v*)(hl + baseO + 4);
        float E[8], O[8];
#pragma unroll
        for (int i = 0; i < 4; ++i) {
          E[i] = bf2f(e0[i]); E[i + 4] = bf2f(e1[i]);
          O[i] = bf2f(o0[i]); O[i + 4] = bf2f(o1[i]);
        }
        float rx[8];
        rx[0] = 0.25f*O[0] + 0.75f*E[0] + 0.75f*O[1] + 0.25f*E[1];
        rx[1] = 0.25f*E[0] + 0.75f*O[1] + 0.75f*E[1] + 0.25f*O[2];
        rx[2] = 0.25f*O[1] + 0.75f*E[1] + 0.75f*O[2] + 0.25f*E[2];
        rx[3] = 0.25f*E[1] + 0.75f*O[2] + 0.75f*E[2] + 0.25f*O[3];
        rx[4] = 0.25f*O[2] + 0.75f*E[2] + 0.75f*O[3] + 0.25f*E[3];
        rx[5] = 0.25f*E[2] + 0.75f*O[3] + 0.75f*E[3] + 0.25f*O[4];
        rx[6] = 0.25f*O[3] + 0.75f*E[3] + 0.75f*O[4] + 0.25f*E[4];
        rx[7] = 0.25f*E[3] + 0.75f*O[4] + 0.75f*E[4] + 0.25f*O[5];
        const float ky = kf4[du];
#pragma unroll
        for (int xx = 0; xx < 8; ++xx) o[xx] += ky * rx[xx];
      }
      const int oc = octile * 64 + mf * 32 + ocl;
      const int Y = atile * 16 + Yl;
      const int X0 = btile * 32 + g * 8;
      float* op = out + (((size_t)(n * 256 + oc)) * 128 + Y) * 128 + X0;
      f32x4v v0, v1;
      v0[0] = o[0]; v0[1] = o[1]; v0[2] = o[2]; v0[3] = o[3];
      v1[0] = o[4]; v1[1] = o[5]; v1[2] = o[6]; v1[3] = o[7];
      *(f32x4v*)op = v0;
      *(f32x4v*)(op + 4) = v1;
    }
  }
}

extern "C" void kernel_launch(void* const* d_in, const int* in_sizes, int n_in,
                              void* d_out, int out_size, void* d_ws, size_t ws_size,
                              hipStream_t stream) {
  (void)in_sizes; (void)n_in; (void)out_size; (void)d_ws; (void)ws_size;
  const float* x = (const float*)d_in[0];
  const float* w = (const float*)d_in[1];
  float* out = (float*)d_out;
  // grid = 4 octiles x 4 n x 32 spatial = 512 blocks, 512 threads
  hipLaunchKernelGGL(fir_up_v18, dim3(512), dim3(512), 0, stream, x, w, out);
}